// Round 13
// baseline (544.036 us; speedup 1.0000x reference)
//
#include <hip/hip_runtime.h>
#include <math.h>

// Problem constants (from reference setup_inputs)
static constexpr int N_NODES = 50000;
static constexpr int N_EDGES = 800000;
static constexpr int IN_F = 128;
static constexpr int CH = 64;
static constexpr int HC = 256;            // NH*CH
static constexpr float NEG_SLOPE = 0.2f;

typedef __attribute__((ext_vector_type(8))) short bf16x8;
typedef __attribute__((ext_vector_type(4))) float f32x4;

// pack two f32 into two bf16 (round-half-up): a -> low16, b -> high16
__device__ __forceinline__ unsigned pack_bf(float a, float b) {
    unsigned ua = __float_as_uint(a) + 0x8000u;
    unsigned ub = __float_as_uint(b) + 0x8000u;
    return __builtin_amdgcn_perm(ub, ua, 0x07060302u);
}
__device__ __forceinline__ float bflo(unsigned u) { return __uint_as_float(u << 16); }
__device__ __forceinline__ float bfhi(unsigned u) { return __uint_as_float(u & 0xffff0000u); }
__device__ __forceinline__ float bfs(unsigned short u) {
    return __uint_as_float((unsigned)u << 16);
}
// fast ELU: v>0 ? v : exp(v)-1 via v_exp_f32 (abs err ~1e-7 vs expm1f)
__device__ __forceinline__ float elu(float v) { return v > 0.f ? v : __expf(v) - 1.0f; }

// position <-> true-channel permutation for xsb storage (involution)
__device__ __forceinline__ int sigma(int p) { return ((p & 15) << 4) | (p >> 4); }

static constexpr int EB_BLK = (N_EDGES + 255) / 256;        // 3125
static constexpr int CONV_ITEMS = 106496 + 32;
static constexpr int CONV_BLK = (CONV_ITEMS + 255) / 256;   // 417
static constexpr int GEMM_BLKS = (N_NODES + 63) / 64;       // 782 (64 rows/block)

// ================= CSR build =================
// merged: blocks [0,EB_BLK) histogram; blocks [EB_BLK, +CONV_BLK) weight convert
__global__ void hist_conv(const int* __restrict__ ei, int* __restrict__ deg,
                          const float* __restrict__ W1, const float* __restrict__ W2,
                          const float* __restrict__ Ws, const float* __restrict__ We1,
                          const float* __restrict__ atte1, const float* __restrict__ We2,
                          const float* __restrict__ atte2, unsigned short* __restrict__ WT1,
                          unsigned short* __restrict__ WT2, unsigned short* __restrict__ WTs,
                          float* __restrict__ weff) {
    if (blockIdx.x < EB_BLK) {
        int e = blockIdx.x * 256 + threadIdx.x;
        if (e < N_EDGES) atomicAdd(&deg[ei[N_EDGES + e]], 1);
        return;
    }
    int t = (blockIdx.x - EB_BLK) * 256 + threadIdx.x;
    if (t < 32768) {  // W1: [128][256]
        int k = t >> 8, n = t & 255;
        unsigned u = __float_as_uint(W1[t]) + 0x8000u;
        WT1[n * 128 + k] = (unsigned short)(u >> 16);
    } else if (t < 98304) {  // W2: [256][256], k-row sigma-permuted
        int u2 = t - 32768;
        int k = u2 >> 8, n = u2 & 255;
        unsigned u = __float_as_uint(W2[u2]) + 0x8000u;
        WT2[n * 256 + sigma(k)] = (unsigned short)(u >> 16);
    } else if (t < 106496) {  // skip_W: [128][64]
        int u2 = t - 98304;
        int k = u2 >> 6, n = u2 & 63;
        unsigned u = __float_as_uint(Ws[u2]) + 0x8000u;
        WTs[n * 128 + k] = (unsigned short)(u >> 16);
    } else if (t < 106496 + 32) {  // weff[0..15]=layer1, [16..31]=layer2
        int idx = t - 106496;
        const float* We = idx < 16 ? We1 : We2;
        const float* ae = idx < 16 ? atte1 : atte2;
        int j = idx & 15;
        int d = j >> 2, h = j & 3;
        float s = 0.f;
        for (int c = 0; c < CH; ++c) s += We[d * HC + h * CH + c] * ae[h * CH + c];
        weff[idx] = s;
    }
}

__global__ void scan_block(const int* __restrict__ deg, int* __restrict__ rowptr,
                           int* __restrict__ bsum) {
    __shared__ int s[256];
    int tid = threadIdx.x;
    int i = blockIdx.x * 256 + tid;
    int v = (i < N_NODES) ? deg[i] : 0;
    s[tid] = v;
    __syncthreads();
    for (int off = 1; off < 256; off <<= 1) {
        int t = (tid >= off) ? s[tid - off] : 0;
        __syncthreads();
        s[tid] += t;
        __syncthreads();
    }
    if (i < N_NODES) rowptr[i] = s[tid] - v;  // exclusive
    if (tid == 255) bsum[blockIdx.x] = s[255];
}

// scan of block sums folded in: every block redundantly scans bsum in LDS
__global__ void scan_add2(int* __restrict__ rowptr, const int* __restrict__ bsum,
                          int* __restrict__ fillc, int nb) {
    __shared__ int s[256];
    int tid = threadIdx.x;
    int v = (tid < nb) ? bsum[tid] : 0;
    s[tid] = v;
    __syncthreads();
    for (int off = 1; off < 256; off <<= 1) {
        int t = (tid >= off) ? s[tid - off] : 0;
        __syncthreads();
        s[tid] += t;
        __syncthreads();
    }
    int boff = (blockIdx.x == 0) ? 0 : s[blockIdx.x - 1];  // exclusive block offset
    int i = blockIdx.x * 256 + tid;
    if (i < N_NODES) {
        rowptr[i] += boff;
        fillc[i] = 0;
    }
    if (i == N_NODES) rowptr[N_NODES] = N_EDGES;
}

// fills csr_src (4B scatter -- the only scattered write) + pos[e] (sequential)
__global__ void csr_fill(const int* __restrict__ ei, const int* __restrict__ rowptr,
                         int* __restrict__ fillc, int* __restrict__ csr_src,
                         int* __restrict__ pos) {
    int e = blockIdx.x * blockDim.x + threadIdx.x;
    if (e >= N_EDGES) return;
    int s = ei[e];
    int t = ei[N_EDGES + e];
    int p = atomicAdd(&fillc[t], 1);
    int i = rowptr[t] + p;
    csr_src[i] = s;
    pos[e] = i;
}

// ---------- LDS-free bf16 MFMA GEMM + fused attention epilogue ----------
// 64 rows/block (1 MFMA row-tile per wave) -> 782 blocks, ~112 VGPR: high
// occupancy for this latency-bound kernel.
// A: fp32 (ABF=false) or bf16 position-major (ABF=true, BN+ELU in-register;
// scale/shift computed from colsum/colsq in an LDS prologue).
// SKIP=true additionally computes residual = A @ skip_W + skip_b (fp32 [M][64]).
// Writes xsb bf16 [M][256] POSITION-MAJOR (pos p holds true channel sigma(p)).
template <int K, bool ABF, bool BN, bool SKIP>
__global__ __launch_bounds__(256) void gemm_mfma_att(
    const void* __restrict__ Av, const unsigned short* __restrict__ BT,
    const float* __restrict__ colsum, const float* __restrict__ g,
    const float* __restrict__ be, float invM,
    const unsigned short* __restrict__ BTs, const float* __restrict__ skip_b,
    float* __restrict__ residual,
    const float* __restrict__ att_src, const float* __restrict__ att_dst,
    unsigned short* __restrict__ xsb, float* __restrict__ asrc, float* __restrict__ adst,
    int M) {
    constexpr int NT = 16;
    __shared__ float s_scale[256], s_shift[256];
    if constexpr (BN) {
        int c = threadIdx.x;
        int tc = sigma(c);
        float mean = colsum[c] * invM;
        float var = colsum[256 + c] * invM - mean * mean;
        float sc = g[tc] * rsqrtf(var + 1e-5f);
        s_scale[c] = sc;
        s_shift[c] = be[tc] - mean * sc;
        __syncthreads();
    }
    const int lane = threadIdx.x & 63;
    const int wid = threadIdx.x >> 6;
    const int r0 = blockIdx.x * 64 + wid * 16;
    const int lr = lane & 15;
    const int kg = lane >> 4;
    f32x4 acc[NT] = {};
    f32x4 accS[4] = {};
    const float* af = (const float*)Av;
    const unsigned short* ab = (const unsigned short*)Av;
    int rr = r0 + lr;
    if (rr >= M) rr = M - 1;
    const size_t rowoff = (size_t)rr * K + kg * 8;
    const unsigned short* brow = BT + (size_t)lr * K + kg * 8;
    const unsigned short* brow_s = SKIP ? BTs + (size_t)lr * K + kg * 8 : nullptr;
    for (int k0 = 0; k0 < K; k0 += 32) {
        float4 sc0, sc1, sh0, sh1;
        if constexpr (BN) {
            sc0 = *reinterpret_cast<const float4*>(&s_scale[k0 + kg * 8]);
            sc1 = *reinterpret_cast<const float4*>(&s_scale[k0 + kg * 8 + 4]);
            sh0 = *reinterpret_cast<const float4*>(&s_shift[k0 + kg * 8]);
            sh1 = *reinterpret_cast<const float4*>(&s_shift[k0 + kg * 8 + 4]);
        }
        bf16x8 a;
        if constexpr (!ABF) {
            const float4 lo = *reinterpret_cast<const float4*>(af + rowoff + k0);
            const float4 hi = *reinterpret_cast<const float4*>(af + rowoff + k0 + 4);
            union { bf16x8 v; unsigned u[4]; } fa;
            fa.u[0] = pack_bf(lo.x, lo.y);
            fa.u[1] = pack_bf(lo.z, lo.w);
            fa.u[2] = pack_bf(hi.x, hi.y);
            fa.u[3] = pack_bf(hi.z, hi.w);
            a = fa.v;
        } else {
            union { bf16x8 v; unsigned short us[8]; unsigned u[4]; } fa;
            fa.v = *reinterpret_cast<const bf16x8*>(ab + rowoff + k0);
            if constexpr (BN) {
                float f0 = elu(fmaf(bfs(fa.us[0]), sc0.x, sh0.x));
                float f1 = elu(fmaf(bfs(fa.us[1]), sc0.y, sh0.y));
                float f2 = elu(fmaf(bfs(fa.us[2]), sc0.z, sh0.z));
                float f3 = elu(fmaf(bfs(fa.us[3]), sc0.w, sh0.w));
                float f4 = elu(fmaf(bfs(fa.us[4]), sc1.x, sh1.x));
                float f5 = elu(fmaf(bfs(fa.us[5]), sc1.y, sh1.y));
                float f6 = elu(fmaf(bfs(fa.us[6]), sc1.z, sh1.z));
                float f7 = elu(fmaf(bfs(fa.us[7]), sc1.w, sh1.w));
                fa.u[0] = pack_bf(f0, f1);
                fa.u[1] = pack_bf(f2, f3);
                fa.u[2] = pack_bf(f4, f5);
                fa.u[3] = pack_bf(f6, f7);
            }
            a = fa.v;
        }
#pragma unroll
        for (int c = 0; c < NT; ++c) {
            bf16x8 b = *reinterpret_cast<const bf16x8*>(brow + (size_t)c * 16 * K + k0);
            acc[c] = __builtin_amdgcn_mfma_f32_16x16x32_bf16(a, b, acc[c], 0, 0, 0);
        }
        if constexpr (SKIP) {
#pragma unroll
            for (int c = 0; c < 4; ++c) {
                bf16x8 b = *reinterpret_cast<const bf16x8*>(brow_s + (size_t)c * 16 * K + k0);
                accS[c] = __builtin_amdgcn_mfma_f32_16x16x32_bf16(a, b, accS[c], 0, 0, 0);
            }
        }
    }
    // epilogue: position-major bf16 feature write (wide stores) + per-row att dots
    float attS[NT], attD[NT];
#pragma unroll
    for (int c = 0; c < NT; ++c) {
        attS[c] = att_src[c * 16 + lr];
        attD[c] = att_dst[c * 16 + lr];
    }
#pragma unroll
    for (int j = 0; j < 4; ++j) {
        int row = r0 + kg * 4 + j;
        bool valid = row < M;
        uint4 ua, ub;
        ua.x = pack_bf(acc[0][j], acc[1][j]);
        ua.y = pack_bf(acc[2][j], acc[3][j]);
        ua.z = pack_bf(acc[4][j], acc[5][j]);
        ua.w = pack_bf(acc[6][j], acc[7][j]);
        ub.x = pack_bf(acc[8][j], acc[9][j]);
        ub.y = pack_bf(acc[10][j], acc[11][j]);
        ub.z = pack_bf(acc[12][j], acc[13][j]);
        ub.w = pack_bf(acc[14][j], acc[15][j]);
        if (valid) {
            uint4* dst = reinterpret_cast<uint4*>(xsb + (size_t)row * HC) + lr * 2;
            dst[0] = ua;
            dst[1] = ub;
        }
        if constexpr (SKIP) {
            if (valid) {
#pragma unroll
                for (int c = 0; c < 4; ++c) {
                    int col = c * 16 + lr;
                    residual[(size_t)row * CH + col] = accS[c][j] + skip_b[col];
                }
            }
        }
#pragma unroll
        for (int h = 0; h < 4; ++h) {
            float ps = acc[4 * h + 0][j] * attS[4 * h + 0] +
                       acc[4 * h + 1][j] * attS[4 * h + 1] +
                       acc[4 * h + 2][j] * attS[4 * h + 2] +
                       acc[4 * h + 3][j] * attS[4 * h + 3];
            float pd = acc[4 * h + 0][j] * attD[4 * h + 0] +
                       acc[4 * h + 1][j] * attD[4 * h + 1] +
                       acc[4 * h + 2][j] * attD[4 * h + 2] +
                       acc[4 * h + 3][j] * attD[4 * h + 3];
#pragma unroll
            for (int mk = 1; mk < 16; mk <<= 1) {
                ps += __shfl_xor(ps, mk);
                pd += __shfl_xor(pd, mk);
            }
            if (valid && lr == 0) {
                asrc[row * 4 + h] = ps;
                adst[row * 4 + h] = pd;
            }
        }
    }
}

// ---------- edge-parallel attention weights (original edge order) ----------
// Sequential ei/ea/pos reads; asrc/adst gathers hit the 800KB L2-resident
// tables; pw 16B scatter is the only scattered write.
__global__ __launch_bounds__(256) void edge_w(
    const int* __restrict__ ei, const float4* __restrict__ ea, const int* __restrict__ pos,
    const float* __restrict__ weff, const float4* __restrict__ asrcv,
    const float4* __restrict__ adstv, uint4* __restrict__ pw) {
    int e = blockIdx.x * 256 + threadIdx.x;
    if (e >= N_EDGES) return;
    int s = ei[e];
    int t = ei[N_EDGES + e];
    const float4 v = ea[e];
    const float4 as4 = asrcv[s];
    const float4 ad4 = adstv[t];
    const float asl[4] = {as4.x, as4.y, as4.z, as4.w};
    const float adl[4] = {ad4.x, ad4.y, ad4.z, ad4.w};
    float p[4], aev[4];
#pragma unroll
    for (int h = 0; h < 4; ++h) {
        float ae = v.x * weff[h] + v.y * weff[4 + h] + v.z * weff[8 + h] + v.w * weff[12 + h];
        float l = asl[h] + adl[h] + ae;
        l = fmaxf(l, NEG_SLOPE * l);  // leaky relu (0<slope<1)
        p[h] = __expf(l);
        aev[h] = ae;
    }
    pw[pos[e]] = make_uint4(pack_bf(p[0], p[1]), pack_bf(p[2], p[3]),
                            pack_bf(aev[0], aev[1]), pack_bf(aev[2], aev[3]));
}

// ---------- lean gather-aggregate over CSR (position-major features) ----------
// One wave per node; lane covers positions 4l..4l+3, all of head (lane&3).
// D=8 main loop + serial remainder (proven optimum r7/r10). Block 0 zeroes the
// colsum/colsq buffer for the following colstats dispatch.
template <bool MEAN>
__global__ __launch_bounds__(256) void gat_node(
    const int* __restrict__ rowptr, const int* __restrict__ csr_src,
    const uint4* __restrict__ pw, const float4* __restrict__ asrcv,
    const float4* __restrict__ adstv, const uint2* __restrict__ xsb,
    float* __restrict__ zbuf, void* __restrict__ outp) {
    if (blockIdx.x == 0) {
        zbuf[threadIdx.x] = 0.f;
        zbuf[256 + threadIdx.x] = 0.f;
    }
    int t = blockIdx.x * 4 + (threadIdx.x >> 6);
    if (t >= N_NODES) return;
    const int lane = threadIdx.x & 63;
    const int h = lane & 3;                        // head for this lane (position-major)
    const unsigned sh = (h & 1) ? 0u : 16u;        // own bf16 -> high bits
    const bool hiW = (h & 2) != 0;
    const int start = rowptr[t], end = rowptr[t + 1];
    const int deg = end - start;
    const uint2* xl = xsb + lane;
    float acc0 = 0.f, acc1 = 0.f, acc2 = 0.f, acc3 = 0.f;
    float psum = 0.f, aesum = 0.f;
    int i = start;
    for (; i + 8 <= end; i += 8) {
        uint2 f[8];
        float p[8], ae[8];
#pragma unroll
        for (int j = 0; j < 8; ++j) {
            int s = csr_src[i + j];
            f[j] = xl[(size_t)s * 64];
            const uint4 w = pw[i + j];
            unsigned pword = hiW ? w.y : w.x;
            unsigned aeword = hiW ? w.w : w.z;
            p[j] = __uint_as_float((pword << sh) & 0xffff0000u);
            ae[j] = __uint_as_float((aeword << sh) & 0xffff0000u);
        }
#pragma unroll
        for (int j = 0; j < 8; ++j) {
            psum += p[j];
            aesum += ae[j];
            acc0 += bflo(f[j].x) * p[j];
            acc1 += bfhi(f[j].x) * p[j];
            acc2 += bflo(f[j].y) * p[j];
            acc3 += bfhi(f[j].y) * p[j];
        }
    }
    for (; i < end; ++i) {
        int s = csr_src[i];
        uint2 f = xl[(size_t)s * 64];
        const uint4 w = pw[i];
        unsigned pword = hiW ? w.y : w.x;
        unsigned aeword = hiW ? w.w : w.z;
        float p = __uint_as_float((pword << sh) & 0xffff0000u);
        float ae = __uint_as_float((aeword << sh) & 0xffff0000u);
        psum += p;
        aesum += ae;
        acc0 += bflo(f.x) * p;
        acc1 += bfhi(f.x) * p;
        acc2 += bflo(f.y) * p;
        acc3 += bfhi(f.y) * p;
    }
    // self loop
    const float inv_deg = deg > 0 ? 1.0f / (float)deg : 1.0f;
    const float4 as4 = asrcv[t];
    const float4 ad4 = adstv[t];
    float asl = h == 0 ? as4.x : h == 1 ? as4.y : h == 2 ? as4.z : as4.w;
    float adl = h == 0 ? ad4.x : h == 1 ? ad4.y : h == 2 ? ad4.z : ad4.w;
    float l = asl + adl + aesum * inv_deg;
    l = fmaxf(l, NEG_SLOPE * l);
    const float pself = __expf(l);
    uint2 sf = xl[(size_t)t * 64];
    acc0 += bflo(sf.x) * pself;
    acc1 += bfhi(sf.x) * pself;
    acc2 += bflo(sf.y) * pself;
    acc3 += bfhi(sf.y) * pself;
    const float inv = 1.0f / (psum + pself + 1e-16f);
    acc0 *= inv; acc1 *= inv; acc2 *= inv; acc3 *= inv;
    if constexpr (MEAN) {
        // heads live in lane bits 0,1 -> sum across them
        acc0 += __shfl_xor(acc0, 1); acc0 += __shfl_xor(acc0, 2);
        acc1 += __shfl_xor(acc1, 1); acc1 += __shfl_xor(acc1, 2);
        acc2 += __shfl_xor(acc2, 1); acc2 += __shfl_xor(acc2, 2);
        acc3 += __shfl_xor(acc3, 1); acc3 += __shfl_xor(acc3, 2);
        if (h == 0) {
            int q = lane >> 2;  // within-head channel base
            float* o = reinterpret_cast<float*>(outp) + (size_t)t * CH + q;
            o[0] = 0.25f * acc0;
            o[16] = 0.25f * acc1;
            o[32] = 0.25f * acc2;
            o[48] = 0.25f * acc3;
        }
    } else {
        // position-major bf16 write (same layout as xsb)
        reinterpret_cast<uint2*>(outp)[(size_t)t * 64 + lane] =
            make_uint2(pack_bf(acc0, acc1), pack_bf(acc2, acc3));
    }
}

// ---------- BN column stats (bf16 position-major input, F=256) ----------
__global__ void colstats_bf(const unsigned short* __restrict__ X, float* __restrict__ sum,
                            float* __restrict__ sumsq, int M) {
    int c = threadIdx.x;  // position index
    int r0 = blockIdx.x * 256;
    int r1 = min(M, r0 + 256);
    float s = 0.f, q = 0.f;
    for (int r = r0; r < r1; ++r) {
        float v = bfs(X[(size_t)r * HC + c]);
        s += v;
        q += v * v;
    }
    atomicAdd(&sum[c], s);
    atomicAdd(&sumsq[c], q);
}

// ---------- BN column stats (fp32) ----------
template <int F>
__global__ void colstats(const float* __restrict__ X, float* __restrict__ sum,
                         float* __restrict__ sumsq, int M) {
    const int NG = 256 / F;
    int c = threadIdx.x % F;
    int g = threadIdx.x / F;
    int r0 = blockIdx.x * 256;
    int r1 = min(M, r0 + 256);
    float s = 0.f, q = 0.f;
    for (int r = r0 + g; r < r1; r += NG) {
        float v = X[(size_t)r * F + c];
        s += v;
        q += v * v;
    }
    atomicAdd(&sum[c], s);
    atomicAdd(&sumsq[c], q);
}

// ---------- fused BN2-finalize + BN2+ELU+residual + MLP head ----------
__global__ __launch_bounds__(256) void head_mlp(
    const float* __restrict__ h2, const float* __restrict__ colsum,
    const float* __restrict__ g2, const float* __restrict__ be2, float invM,
    const float* __restrict__ residual, const float* __restrict__ fc1W,
    const float* __restrict__ fc1b, const float* __restrict__ fc2W,
    const float* __restrict__ fc2b, float* __restrict__ out) {
    __shared__ float s_sc[CH], s_sh[CH];
    if (threadIdx.x < CH) {
        int c = threadIdx.x;
        float mean = colsum[c] * invM;
        float var = colsum[256 + c] * invM - mean * mean;
        float sc = g2[c] * rsqrtf(var + 1e-5f);
        s_sc[c] = sc;
        s_sh[c] = be2[c] - mean * sc;
    }
    __syncthreads();
    int n = blockIdx.x * 4 + (threadIdx.x >> 6);
    if (n >= N_NODES) return;
    int w = threadIdx.x >> 6;
    int lane = threadIdx.x & 63;
    __shared__ float hrow[4][64];
    float v = fmaf(h2[(size_t)n * CH + lane], s_sc[lane], s_sh[lane]);
    v = elu(v) + residual[(size_t)n * CH + lane];
    hrow[w][lane] = v;
    // same-wave LDS write->read: DS ops execute in order per wave
    float p = 0.f;
    if (lane < 32) {
        float acc = fc1b[lane];
#pragma unroll
        for (int k = 0; k < CH; ++k) acc = fmaf(hrow[w][k], fc1W[k * 32 + lane], acc);
        acc = fmaxf(acc, 0.f);
        p = acc * fc2W[lane];
    }
    for (int off = 16; off > 0; off >>= 1) p += __shfl_down(p, off);
    if (lane == 0) {
        float z = p + fc2b[0];
        out[n] = z > 20.f ? z : log1pf(expf(z));
    }
}

extern "C" void kernel_launch(void* const* d_in, const int* in_sizes, int n_in, void* d_out,
                              int out_size, void* d_ws, size_t ws_size, hipStream_t stream) {
    const float* x        = (const float*)d_in[0];
    const int*   ei       = (const int*)d_in[1];
    const float* ea       = (const float*)d_in[2];
    const float* W1       = (const float*)d_in[3];
    const float* att_src1 = (const float*)d_in[4];
    const float* att_dst1 = (const float*)d_in[5];
    const float* We1      = (const float*)d_in[6];
    const float* att_e1   = (const float*)d_in[7];
    const float* g1       = (const float*)d_in[9];
    const float* be1      = (const float*)d_in[10];
    const float* W2       = (const float*)d_in[11];
    const float* att_src2 = (const float*)d_in[12];
    const float* att_dst2 = (const float*)d_in[13];
    const float* We2      = (const float*)d_in[14];
    const float* att_e2   = (const float*)d_in[15];
    const float* g2       = (const float*)d_in[17];
    const float* be2      = (const float*)d_in[18];
    const float* skip_W   = (const float*)d_in[19];
    const float* skip_b   = (const float*)d_in[20];
    const float* fc1_W    = (const float*)d_in[21];
    const float* fc1_b    = (const float*)d_in[22];
    const float* fc2_W    = (const float*)d_in[23];
    const float* fc2_b    = (const float*)d_in[24];
    float* out = (float*)d_out;

    float* wsf = (float*)d_ws;
    size_t off = 0;
    auto take = [&](size_t n) {
        float* p = wsf + off;
        off += n;
        return p;
    };
    unsigned short* xsb  = (unsigned short*)take((size_t)N_NODES * HC / 2);  // bf16 [N][256] pos-major
    unsigned short* aggb = (unsigned short*)take((size_t)N_NODES * HC / 2);  // bf16 [N][256] pos-major
    uint4* pw       = (uint4*)take((size_t)N_EDGES * 4);   // packed {p[4],ae[4]} per CSR slot
    int* csr_src    = (int*)take(N_EDGES);
    int* pos        = (int*)take(N_EDGES);
    int* rowptr     = (int*)take(N_NODES + 1);
    int* degfill    = (int*)take(N_NODES);                 // deg, then fill counter
    int* bsum       = (int*)take(256);
    float* asrc     = take(N_NODES * 4);
    float* adst     = take(N_NODES * 4);
    float* residual = take((size_t)N_NODES * CH);
    float* h2       = take((size_t)N_NODES * CH);
    float* weff     = take(32);                            // [0..15] L1, [16..31] L2
    float* colsum   = take(HC);
    float* colsq    = take(HC);                            // contiguous: colsum+256
    unsigned short* WT1 = (unsigned short*)take(IN_F * HC / 2);
    unsigned short* WT2 = (unsigned short*)take(HC * HC / 2);
    unsigned short* WTs = (unsigned short*)take(IN_F * CH / 2);

    const int NBLK = (N_NODES + 255) / 256;
    const int NODE4 = (N_NODES + 3) / 4;
    const float invM = 1.0f / N_NODES;

    // ===== CSR degree/scan + weight conversion (merged) =====
    hipMemsetAsync(degfill, 0, N_NODES * sizeof(int), stream);
    hist_conv<<<EB_BLK + CONV_BLK, 256, 0, stream>>>(ei, degfill, W1, W2, skip_W, We1,
                                                     att_e1, We2, att_e2, WT1, WT2, WTs, weff);
    scan_block<<<NBLK, 256, 0, stream>>>(degfill, rowptr, bsum);
    scan_add2<<<(N_NODES + 256) / 256, 256, 0, stream>>>(rowptr, bsum, degfill, NBLK);
    csr_fill<<<EB_BLK, 256, 0, stream>>>(ei, rowptr, degfill, csr_src, pos);

    // ===== GAT layer 1 (+ fused skip GEMM) =====
    gemm_mfma_att<IN_F, false, false, true><<<GEMM_BLKS, 256, 0, stream>>>(
        x, WT1, nullptr, nullptr, nullptr, 0.f, WTs, skip_b, residual, att_src1, att_dst1,
        xsb, asrc, adst, N_NODES);
    edge_w<<<EB_BLK, 256, 0, stream>>>(ei, (const float4*)ea, pos, weff, (const float4*)asrc,
                                       (const float4*)adst, pw);
    gat_node<false><<<NODE4, 256, 0, stream>>>(rowptr, csr_src, pw, (const float4*)asrc,
                                               (const float4*)adst, (const uint2*)xsb,
                                               colsum, aggb);
    // BN1 stats in position space (b1 cancels); finalize fused into gemm2 prologue
    colstats_bf<<<NBLK, 256, 0, stream>>>(aggb, colsum, colsq, N_NODES);

    // ===== GAT layer 2 (BN1 finalize+apply fused into bf16 A-load) =====
    gemm_mfma_att<HC, true, true, false><<<GEMM_BLKS, 256, 0, stream>>>(
        aggb, WT2, colsum, g1, be1, invM, nullptr, nullptr, nullptr, att_src2, att_dst2,
        xsb, asrc, adst, N_NODES);
    edge_w<<<EB_BLK, 256, 0, stream>>>(ei, (const float4*)ea, pos, weff + 16,
                                       (const float4*)asrc, (const float4*)adst, pw);
    gat_node<true><<<NODE4, 256, 0, stream>>>(rowptr, csr_src, pw, (const float4*)asrc,
                                              (const float4*)adst, (const uint2*)xsb,
                                              colsum, h2);
    // BN2 stats on h2 (true-channel space, b2 cancels); finalize fused into head
    colstats<CH><<<NBLK, 256, 0, stream>>>(h2, colsum, colsq, N_NODES);

    // fused BN2-finalize + BN2+ELU+residual + MLP head
    head_mlp<<<NODE4, 256, 0, stream>>>(h2, colsum, g2, be2, invM, residual, fc1_W, fc1_b,
                                        fc2_W, fc2_b, out);
}

// Round 14
// 487.122 us; speedup vs baseline: 1.1168x; 1.1168x over previous
//
#include <hip/hip_runtime.h>
#include <math.h>

// Problem constants (from reference setup_inputs)
static constexpr int N_NODES = 50000;
static constexpr int N_EDGES = 800000;
static constexpr int IN_F = 128;
static constexpr int CH = 64;
static constexpr int HC = 256;            // NH*CH
static constexpr float NEG_SLOPE = 0.2f;

typedef __attribute__((ext_vector_type(8))) short bf16x8;
typedef __attribute__((ext_vector_type(4))) float f32x4;

// pack two f32 into two bf16 (round-half-up): a -> low16, b -> high16
__device__ __forceinline__ unsigned pack_bf(float a, float b) {
    unsigned ua = __float_as_uint(a) + 0x8000u;
    unsigned ub = __float_as_uint(b) + 0x8000u;
    return __builtin_amdgcn_perm(ub, ua, 0x07060302u);
}
__device__ __forceinline__ float bflo(unsigned u) { return __uint_as_float(u << 16); }
__device__ __forceinline__ float bfhi(unsigned u) { return __uint_as_float(u & 0xffff0000u); }
__device__ __forceinline__ float bfs(unsigned short u) {
    return __uint_as_float((unsigned)u << 16);
}
// fast ELU: v>0 ? v : exp(v)-1 via v_exp_f32 (abs err ~1e-7 vs expm1f)
__device__ __forceinline__ float elu(float v) { return v > 0.f ? v : __expf(v) - 1.0f; }

// position <-> true-channel permutation for xsb storage (involution)
__device__ __forceinline__ int sigma(int p) { return ((p & 15) << 4) | (p >> 4); }

static constexpr int EB_BLK = (N_EDGES + 255) / 256;        // 3125
static constexpr int CONV_ITEMS = 106496 + 32;
static constexpr int CONV_BLK = (CONV_ITEMS + 255) / 256;   // 417
static constexpr int GEMM_BLKS = (N_NODES + 63) / 64;       // 782 (64 rows/block)

// ================= CSR build =================
// merged: blocks [0,EB_BLK) histogram; blocks [EB_BLK, +CONV_BLK) weight convert
__global__ void hist_conv(const int* __restrict__ ei, int* __restrict__ deg,
                          const float* __restrict__ W1, const float* __restrict__ W2,
                          const float* __restrict__ Ws, const float* __restrict__ We1,
                          const float* __restrict__ atte1, const float* __restrict__ We2,
                          const float* __restrict__ atte2, unsigned short* __restrict__ WT1,
                          unsigned short* __restrict__ WT2, unsigned short* __restrict__ WTs,
                          float* __restrict__ weff) {
    if (blockIdx.x < EB_BLK) {
        int e = blockIdx.x * 256 + threadIdx.x;
        if (e < N_EDGES) atomicAdd(&deg[ei[N_EDGES + e]], 1);
        return;
    }
    int t = (blockIdx.x - EB_BLK) * 256 + threadIdx.x;
    if (t < 32768) {  // W1: [128][256]
        int k = t >> 8, n = t & 255;
        unsigned u = __float_as_uint(W1[t]) + 0x8000u;
        WT1[n * 128 + k] = (unsigned short)(u >> 16);
    } else if (t < 98304) {  // W2: [256][256], k-row sigma-permuted
        int u2 = t - 32768;
        int k = u2 >> 8, n = u2 & 255;
        unsigned u = __float_as_uint(W2[u2]) + 0x8000u;
        WT2[n * 256 + sigma(k)] = (unsigned short)(u >> 16);
    } else if (t < 106496) {  // skip_W: [128][64]
        int u2 = t - 98304;
        int k = u2 >> 6, n = u2 & 63;
        unsigned u = __float_as_uint(Ws[u2]) + 0x8000u;
        WTs[n * 128 + k] = (unsigned short)(u >> 16);
    } else if (t < 106496 + 32) {  // weff[0..15]=layer1, [16..31]=layer2
        int idx = t - 106496;
        const float* We = idx < 16 ? We1 : We2;
        const float* ae = idx < 16 ? atte1 : atte2;
        int j = idx & 15;
        int d = j >> 2, h = j & 3;
        float s = 0.f;
        for (int c = 0; c < CH; ++c) s += We[d * HC + h * CH + c] * ae[h * CH + c];
        weff[idx] = s;
    }
}

__global__ void scan_block(const int* __restrict__ deg, int* __restrict__ rowptr,
                           int* __restrict__ bsum) {
    __shared__ int s[256];
    int tid = threadIdx.x;
    int i = blockIdx.x * 256 + tid;
    int v = (i < N_NODES) ? deg[i] : 0;
    s[tid] = v;
    __syncthreads();
    for (int off = 1; off < 256; off <<= 1) {
        int t = (tid >= off) ? s[tid - off] : 0;
        __syncthreads();
        s[tid] += t;
        __syncthreads();
    }
    if (i < N_NODES) rowptr[i] = s[tid] - v;  // exclusive
    if (tid == 255) bsum[blockIdx.x] = s[255];
}

// scan of block sums folded in: every block redundantly scans bsum in LDS
__global__ void scan_add2(int* __restrict__ rowptr, const int* __restrict__ bsum,
                          int* __restrict__ fillc, int nb) {
    __shared__ int s[256];
    int tid = threadIdx.x;
    int v = (tid < nb) ? bsum[tid] : 0;
    s[tid] = v;
    __syncthreads();
    for (int off = 1; off < 256; off <<= 1) {
        int t = (tid >= off) ? s[tid - off] : 0;
        __syncthreads();
        s[tid] += t;
        __syncthreads();
    }
    int boff = (blockIdx.x == 0) ? 0 : s[blockIdx.x - 1];  // exclusive block offset
    int i = blockIdx.x * 256 + tid;
    if (i < N_NODES) {
        rowptr[i] += boff;
        fillc[i] = 0;
    }
    if (i == N_NODES) rowptr[N_NODES] = N_EDGES;
}

// ---------- LDS-free bf16 MFMA GEMM + fused attention epilogue ----------
// 64 rows/block, 782 gemm blocks. FILL=true: trailing EB_BLK blocks scatter ONE
// 16B record per edge (edrec = {src, dst, ea as 4xbf16}) to its CSR slot --
// single cache line per edge (r12's 3-array/24B scatter cost 143MB HBM writes).
// A: fp32 (ABF=false) or bf16 position-major (ABF=true, BN+ELU in-register;
// scale/shift computed from colsum/colsq in an LDS prologue).
// SKIP=true additionally computes residual = A @ skip_W + skip_b (fp32 [M][64]).
// Writes xsb bf16 [M][256] POSITION-MAJOR (pos p holds true channel sigma(p)).
template <int K, bool ABF, bool BN, bool SKIP, bool FILL>
__global__ __launch_bounds__(256) void gemm_mfma_att(
    const void* __restrict__ Av, const unsigned short* __restrict__ BT,
    const float* __restrict__ colsum, const float* __restrict__ g,
    const float* __restrict__ be, float invM,
    const unsigned short* __restrict__ BTs, const float* __restrict__ skip_b,
    float* __restrict__ residual,
    const float* __restrict__ att_src, const float* __restrict__ att_dst,
    unsigned short* __restrict__ xsb, float* __restrict__ asrc, float* __restrict__ adst,
    int M, const int* __restrict__ ei, const float4* __restrict__ ea,
    const int* __restrict__ rowptr, int* __restrict__ fillc, uint4* __restrict__ edrec) {
    if constexpr (FILL) {
        if (blockIdx.x >= GEMM_BLKS) {
            int e = (blockIdx.x - GEMM_BLKS) * 256 + threadIdx.x;
            if (e < N_EDGES) {
                int s = ei[e];
                int t = ei[N_EDGES + e];
                const float4 v = ea[e];
                int p = atomicAdd(&fillc[t], 1);
                edrec[rowptr[t] + p] =
                    make_uint4((unsigned)s, (unsigned)t, pack_bf(v.x, v.y), pack_bf(v.z, v.w));
            }
            return;
        }
    }
    constexpr int NT = 16;
    __shared__ float s_scale[256], s_shift[256];
    if constexpr (BN) {
        int c = threadIdx.x;
        int tc = sigma(c);
        float mean = colsum[c] * invM;
        float var = colsum[256 + c] * invM - mean * mean;
        float sc = g[tc] * rsqrtf(var + 1e-5f);
        s_scale[c] = sc;
        s_shift[c] = be[tc] - mean * sc;
        __syncthreads();
    }
    const int lane = threadIdx.x & 63;
    const int wid = threadIdx.x >> 6;
    const int r0 = blockIdx.x * 64 + wid * 16;
    const int lr = lane & 15;
    const int kg = lane >> 4;
    f32x4 acc[NT] = {};
    f32x4 accS[4] = {};
    const float* af = (const float*)Av;
    const unsigned short* ab = (const unsigned short*)Av;
    int rr = r0 + lr;
    if (rr >= M) rr = M - 1;
    const size_t rowoff = (size_t)rr * K + kg * 8;
    const unsigned short* brow = BT + (size_t)lr * K + kg * 8;
    const unsigned short* brow_s = SKIP ? BTs + (size_t)lr * K + kg * 8 : nullptr;
    for (int k0 = 0; k0 < K; k0 += 32) {
        float4 sc0, sc1, sh0, sh1;
        if constexpr (BN) {
            sc0 = *reinterpret_cast<const float4*>(&s_scale[k0 + kg * 8]);
            sc1 = *reinterpret_cast<const float4*>(&s_scale[k0 + kg * 8 + 4]);
            sh0 = *reinterpret_cast<const float4*>(&s_shift[k0 + kg * 8]);
            sh1 = *reinterpret_cast<const float4*>(&s_shift[k0 + kg * 8 + 4]);
        }
        bf16x8 a;
        if constexpr (!ABF) {
            const float4 lo = *reinterpret_cast<const float4*>(af + rowoff + k0);
            const float4 hi = *reinterpret_cast<const float4*>(af + rowoff + k0 + 4);
            union { bf16x8 v; unsigned u[4]; } fa;
            fa.u[0] = pack_bf(lo.x, lo.y);
            fa.u[1] = pack_bf(lo.z, lo.w);
            fa.u[2] = pack_bf(hi.x, hi.y);
            fa.u[3] = pack_bf(hi.z, hi.w);
            a = fa.v;
        } else {
            union { bf16x8 v; unsigned short us[8]; unsigned u[4]; } fa;
            fa.v = *reinterpret_cast<const bf16x8*>(ab + rowoff + k0);
            if constexpr (BN) {
                float f0 = elu(fmaf(bfs(fa.us[0]), sc0.x, sh0.x));
                float f1 = elu(fmaf(bfs(fa.us[1]), sc0.y, sh0.y));
                float f2 = elu(fmaf(bfs(fa.us[2]), sc0.z, sh0.z));
                float f3 = elu(fmaf(bfs(fa.us[3]), sc0.w, sh0.w));
                float f4 = elu(fmaf(bfs(fa.us[4]), sc1.x, sh1.x));
                float f5 = elu(fmaf(bfs(fa.us[5]), sc1.y, sh1.y));
                float f6 = elu(fmaf(bfs(fa.us[6]), sc1.z, sh1.z));
                float f7 = elu(fmaf(bfs(fa.us[7]), sc1.w, sh1.w));
                fa.u[0] = pack_bf(f0, f1);
                fa.u[1] = pack_bf(f2, f3);
                fa.u[2] = pack_bf(f4, f5);
                fa.u[3] = pack_bf(f6, f7);
            }
            a = fa.v;
        }
#pragma unroll
        for (int c = 0; c < NT; ++c) {
            bf16x8 b = *reinterpret_cast<const bf16x8*>(brow + (size_t)c * 16 * K + k0);
            acc[c] = __builtin_amdgcn_mfma_f32_16x16x32_bf16(a, b, acc[c], 0, 0, 0);
        }
        if constexpr (SKIP) {
#pragma unroll
            for (int c = 0; c < 4; ++c) {
                bf16x8 b = *reinterpret_cast<const bf16x8*>(brow_s + (size_t)c * 16 * K + k0);
                accS[c] = __builtin_amdgcn_mfma_f32_16x16x32_bf16(a, b, accS[c], 0, 0, 0);
            }
        }
    }
    // epilogue: position-major bf16 feature write (wide stores) + per-row att dots
    float attS[NT], attD[NT];
#pragma unroll
    for (int c = 0; c < NT; ++c) {
        attS[c] = att_src[c * 16 + lr];
        attD[c] = att_dst[c * 16 + lr];
    }
#pragma unroll
    for (int j = 0; j < 4; ++j) {
        int row = r0 + kg * 4 + j;
        bool valid = row < M;
        uint4 ua, ub;
        ua.x = pack_bf(acc[0][j], acc[1][j]);
        ua.y = pack_bf(acc[2][j], acc[3][j]);
        ua.z = pack_bf(acc[4][j], acc[5][j]);
        ua.w = pack_bf(acc[6][j], acc[7][j]);
        ub.x = pack_bf(acc[8][j], acc[9][j]);
        ub.y = pack_bf(acc[10][j], acc[11][j]);
        ub.z = pack_bf(acc[12][j], acc[13][j]);
        ub.w = pack_bf(acc[14][j], acc[15][j]);
        if (valid) {
            uint4* dst = reinterpret_cast<uint4*>(xsb + (size_t)row * HC) + lr * 2;
            dst[0] = ua;
            dst[1] = ub;
        }
        if constexpr (SKIP) {
            if (valid) {
#pragma unroll
                for (int c = 0; c < 4; ++c) {
                    int col = c * 16 + lr;
                    residual[(size_t)row * CH + col] = accS[c][j] + skip_b[col];
                }
            }
        }
#pragma unroll
        for (int h = 0; h < 4; ++h) {
            float ps = acc[4 * h + 0][j] * attS[4 * h + 0] +
                       acc[4 * h + 1][j] * attS[4 * h + 1] +
                       acc[4 * h + 2][j] * attS[4 * h + 2] +
                       acc[4 * h + 3][j] * attS[4 * h + 3];
            float pd = acc[4 * h + 0][j] * attD[4 * h + 0] +
                       acc[4 * h + 1][j] * attD[4 * h + 1] +
                       acc[4 * h + 2][j] * attD[4 * h + 2] +
                       acc[4 * h + 3][j] * attD[4 * h + 3];
#pragma unroll
            for (int mk = 1; mk < 16; mk <<= 1) {
                ps += __shfl_xor(ps, mk);
                pd += __shfl_xor(pd, mk);
            }
            if (valid && lr == 0) {
                asrc[row * 4 + h] = ps;
                adst[row * 4 + h] = pd;
            }
        }
    }
}

// ---------- slot-parallel attention weights (fully sequential I/O) ----------
// edrec is CSR-ordered {src, dst, ea bf16x4}: reads and pw write sequential;
// asrc/adst gathers hit the 800KB L2-resident tables.
__global__ __launch_bounds__(256) void edge_w(
    const uint4* __restrict__ edrec, const float* __restrict__ weff,
    const float4* __restrict__ asrcv, const float4* __restrict__ adstv,
    uint4* __restrict__ pw) {
    int i = blockIdx.x * 256 + threadIdx.x;
    if (i >= N_EDGES) return;
    const uint4 er = edrec[i];
    int s = (int)er.x;
    int t = (int)er.y;
    const float vx = bflo(er.z), vy = bfhi(er.z), vz = bflo(er.w), vw = bfhi(er.w);
    const float4 as4 = asrcv[s];
    const float4 ad4 = adstv[t];
    const float asl[4] = {as4.x, as4.y, as4.z, as4.w};
    const float adl[4] = {ad4.x, ad4.y, ad4.z, ad4.w};
    float p[4], aev[4];
#pragma unroll
    for (int h = 0; h < 4; ++h) {
        float ae = vx * weff[h] + vy * weff[4 + h] + vz * weff[8 + h] + vw * weff[12 + h];
        float l = asl[h] + adl[h] + ae;
        l = fmaxf(l, NEG_SLOPE * l);  // leaky relu (0<slope<1)
        p[h] = __expf(l);
        aev[h] = ae;
    }
    pw[i] = make_uint4(pack_bf(p[0], p[1]), pack_bf(p[2], p[3]),
                       pack_bf(aev[0], aev[1]), pack_bf(aev[2], aev[3]));
}

// ---------- lean gather-aggregate over CSR (position-major features) ----------
// One wave per node; lane covers positions 4l..4l+3, all of head (lane&3).
// D=8 main loop + serial remainder (proven optimum r7/r10). src read from
// edrec[i].x (16B-stride dword). Block 0 zeroes colsum/colsq for colstats.
template <bool MEAN>
__global__ __launch_bounds__(256) void gat_node(
    const int* __restrict__ rowptr, const uint4* __restrict__ edrec,
    const uint4* __restrict__ pw, const float4* __restrict__ asrcv,
    const float4* __restrict__ adstv, const uint2* __restrict__ xsb,
    float* __restrict__ zbuf, void* __restrict__ outp) {
    if (blockIdx.x == 0) {
        zbuf[threadIdx.x] = 0.f;
        zbuf[256 + threadIdx.x] = 0.f;
    }
    int t = blockIdx.x * 4 + (threadIdx.x >> 6);
    if (t >= N_NODES) return;
    const int lane = threadIdx.x & 63;
    const int h = lane & 3;                        // head for this lane (position-major)
    const unsigned sh = (h & 1) ? 0u : 16u;        // own bf16 -> high bits
    const bool hiW = (h & 2) != 0;
    const int start = rowptr[t], end = rowptr[t + 1];
    const int deg = end - start;
    const uint2* xl = xsb + lane;
    const unsigned* er32 = reinterpret_cast<const unsigned*>(edrec);  // src at i*4
    float acc0 = 0.f, acc1 = 0.f, acc2 = 0.f, acc3 = 0.f;
    float psum = 0.f, aesum = 0.f;
    int i = start;
    for (; i + 8 <= end; i += 8) {
        uint2 f[8];
        float p[8], ae[8];
#pragma unroll
        for (int j = 0; j < 8; ++j) {
            int s = (int)er32[(size_t)(i + j) * 4];
            f[j] = xl[(size_t)s * 64];
            const uint4 w = pw[i + j];
            unsigned pword = hiW ? w.y : w.x;
            unsigned aeword = hiW ? w.w : w.z;
            p[j] = __uint_as_float((pword << sh) & 0xffff0000u);
            ae[j] = __uint_as_float((aeword << sh) & 0xffff0000u);
        }
#pragma unroll
        for (int j = 0; j < 8; ++j) {
            psum += p[j];
            aesum += ae[j];
            acc0 += bflo(f[j].x) * p[j];
            acc1 += bfhi(f[j].x) * p[j];
            acc2 += bflo(f[j].y) * p[j];
            acc3 += bfhi(f[j].y) * p[j];
        }
    }
    for (; i < end; ++i) {
        int s = (int)er32[(size_t)i * 4];
        uint2 f = xl[(size_t)s * 64];
        const uint4 w = pw[i];
        unsigned pword = hiW ? w.y : w.x;
        unsigned aeword = hiW ? w.w : w.z;
        float p = __uint_as_float((pword << sh) & 0xffff0000u);
        float ae = __uint_as_float((aeword << sh) & 0xffff0000u);
        psum += p;
        aesum += ae;
        acc0 += bflo(f.x) * p;
        acc1 += bfhi(f.x) * p;
        acc2 += bflo(f.y) * p;
        acc3 += bfhi(f.y) * p;
    }
    // self loop
    const float inv_deg = deg > 0 ? 1.0f / (float)deg : 1.0f;
    const float4 as4 = asrcv[t];
    const float4 ad4 = adstv[t];
    float asl = h == 0 ? as4.x : h == 1 ? as4.y : h == 2 ? as4.z : as4.w;
    float adl = h == 0 ? ad4.x : h == 1 ? ad4.y : h == 2 ? ad4.z : ad4.w;
    float l = asl + adl + aesum * inv_deg;
    l = fmaxf(l, NEG_SLOPE * l);
    const float pself = __expf(l);
    uint2 sf = xl[(size_t)t * 64];
    acc0 += bflo(sf.x) * pself;
    acc1 += bfhi(sf.x) * pself;
    acc2 += bflo(sf.y) * pself;
    acc3 += bfhi(sf.y) * pself;
    const float inv = 1.0f / (psum + pself + 1e-16f);
    acc0 *= inv; acc1 *= inv; acc2 *= inv; acc3 *= inv;
    if constexpr (MEAN) {
        // heads live in lane bits 0,1 -> sum across them
        acc0 += __shfl_xor(acc0, 1); acc0 += __shfl_xor(acc0, 2);
        acc1 += __shfl_xor(acc1, 1); acc1 += __shfl_xor(acc1, 2);
        acc2 += __shfl_xor(acc2, 1); acc2 += __shfl_xor(acc2, 2);
        acc3 += __shfl_xor(acc3, 1); acc3 += __shfl_xor(acc3, 2);
        if (h == 0) {
            int q = lane >> 2;  // within-head channel base
            float* o = reinterpret_cast<float*>(outp) + (size_t)t * CH + q;
            o[0] = 0.25f * acc0;
            o[16] = 0.25f * acc1;
            o[32] = 0.25f * acc2;
            o[48] = 0.25f * acc3;
        }
    } else {
        // position-major bf16 write (same layout as xsb)
        reinterpret_cast<uint2*>(outp)[(size_t)t * 64 + lane] =
            make_uint2(pack_bf(acc0, acc1), pack_bf(acc2, acc3));
    }
}

// ---------- BN column stats (bf16 position-major input, F=256) ----------
__global__ void colstats_bf(const unsigned short* __restrict__ X, float* __restrict__ sum,
                            float* __restrict__ sumsq, int M) {
    int c = threadIdx.x;  // position index
    int r0 = blockIdx.x * 256;
    int r1 = min(M, r0 + 256);
    float s = 0.f, q = 0.f;
    for (int r = r0; r < r1; ++r) {
        float v = bfs(X[(size_t)r * HC + c]);
        s += v;
        q += v * v;
    }
    atomicAdd(&sum[c], s);
    atomicAdd(&sumsq[c], q);
}

// ---------- BN column stats (fp32) ----------
template <int F>
__global__ void colstats(const float* __restrict__ X, float* __restrict__ sum,
                         float* __restrict__ sumsq, int M) {
    const int NG = 256 / F;
    int c = threadIdx.x % F;
    int g = threadIdx.x / F;
    int r0 = blockIdx.x * 256;
    int r1 = min(M, r0 + 256);
    float s = 0.f, q = 0.f;
    for (int r = r0 + g; r < r1; r += NG) {
        float v = X[(size_t)r * F + c];
        s += v;
        q += v * v;
    }
    atomicAdd(&sum[c], s);
    atomicAdd(&sumsq[c], q);
}

// ---------- fused BN2-finalize + BN2+ELU+residual + MLP head ----------
__global__ __launch_bounds__(256) void head_mlp(
    const float* __restrict__ h2, const float* __restrict__ colsum,
    const float* __restrict__ g2, const float* __restrict__ be2, float invM,
    const float* __restrict__ residual, const float* __restrict__ fc1W,
    const float* __restrict__ fc1b, const float* __restrict__ fc2W,
    const float* __restrict__ fc2b, float* __restrict__ out) {
    __shared__ float s_sc[CH], s_sh[CH];
    if (threadIdx.x < CH) {
        int c = threadIdx.x;
        float mean = colsum[c] * invM;
        float var = colsum[256 + c] * invM - mean * mean;
        float sc = g2[c] * rsqrtf(var + 1e-5f);
        s_sc[c] = sc;
        s_sh[c] = be2[c] - mean * sc;
    }
    __syncthreads();
    int n = blockIdx.x * 4 + (threadIdx.x >> 6);
    if (n >= N_NODES) return;
    int w = threadIdx.x >> 6;
    int lane = threadIdx.x & 63;
    __shared__ float hrow[4][64];
    float v = fmaf(h2[(size_t)n * CH + lane], s_sc[lane], s_sh[lane]);
    v = elu(v) + residual[(size_t)n * CH + lane];
    hrow[w][lane] = v;
    // same-wave LDS write->read: DS ops execute in order per wave
    float p = 0.f;
    if (lane < 32) {
        float acc = fc1b[lane];
#pragma unroll
        for (int k = 0; k < CH; ++k) acc = fmaf(hrow[w][k], fc1W[k * 32 + lane], acc);
        acc = fmaxf(acc, 0.f);
        p = acc * fc2W[lane];
    }
    for (int off = 16; off > 0; off >>= 1) p += __shfl_down(p, off);
    if (lane == 0) {
        float z = p + fc2b[0];
        out[n] = z > 20.f ? z : log1pf(expf(z));
    }
}

extern "C" void kernel_launch(void* const* d_in, const int* in_sizes, int n_in, void* d_out,
                              int out_size, void* d_ws, size_t ws_size, hipStream_t stream) {
    const float* x        = (const float*)d_in[0];
    const int*   ei       = (const int*)d_in[1];
    const float* ea       = (const float*)d_in[2];
    const float* W1       = (const float*)d_in[3];
    const float* att_src1 = (const float*)d_in[4];
    const float* att_dst1 = (const float*)d_in[5];
    const float* We1      = (const float*)d_in[6];
    const float* att_e1   = (const float*)d_in[7];
    const float* g1       = (const float*)d_in[9];
    const float* be1      = (const float*)d_in[10];
    const float* W2       = (const float*)d_in[11];
    const float* att_src2 = (const float*)d_in[12];
    const float* att_dst2 = (const float*)d_in[13];
    const float* We2      = (const float*)d_in[14];
    const float* att_e2   = (const float*)d_in[15];
    const float* g2       = (const float*)d_in[17];
    const float* be2      = (const float*)d_in[18];
    const float* skip_W   = (const float*)d_in[19];
    const float* skip_b   = (const float*)d_in[20];
    const float* fc1_W    = (const float*)d_in[21];
    const float* fc1_b    = (const float*)d_in[22];
    const float* fc2_W    = (const float*)d_in[23];
    const float* fc2_b    = (const float*)d_in[24];
    float* out = (float*)d_out;

    float* wsf = (float*)d_ws;
    size_t off = 0;
    auto take = [&](size_t n) {
        float* p = wsf + off;
        off += n;
        return p;
    };
    unsigned short* xsb  = (unsigned short*)take((size_t)N_NODES * HC / 2);  // bf16 [N][256] pos-major
    unsigned short* aggb = (unsigned short*)take((size_t)N_NODES * HC / 2);  // bf16 [N][256] pos-major
    uint4* pw       = (uint4*)take((size_t)N_EDGES * 4);   // packed {p[4],ae[4]} per CSR slot
    uint4* edrec    = (uint4*)take((size_t)N_EDGES * 4);   // {src, dst, ea bf16x4} per slot
    int* rowptr     = (int*)take(N_NODES + 1);
    int* degfill    = (int*)take(N_NODES);                 // deg, then fill counter
    int* bsum       = (int*)take(256);
    float* asrc     = take(N_NODES * 4);
    float* adst     = take(N_NODES * 4);
    float* residual = take((size_t)N_NODES * CH);
    float* h2       = take((size_t)N_NODES * CH);
    float* weff     = take(32);                            // [0..15] L1, [16..31] L2
    float* colsum   = take(HC);
    float* colsq    = take(HC);                            // contiguous: colsum+256
    unsigned short* WT1 = (unsigned short*)take(IN_F * HC / 2);
    unsigned short* WT2 = (unsigned short*)take(HC * HC / 2);
    unsigned short* WTs = (unsigned short*)take(IN_F * CH / 2);

    const int NBLK = (N_NODES + 255) / 256;
    const int NODE4 = (N_NODES + 3) / 4;
    const float invM = 1.0f / N_NODES;

    // ===== CSR degree/scan + weight conversion (merged) =====
    hipMemsetAsync(degfill, 0, N_NODES * sizeof(int), stream);
    hist_conv<<<EB_BLK + CONV_BLK, 256, 0, stream>>>(ei, degfill, W1, W2, skip_W, We1,
                                                     att_e1, We2, att_e2, WT1, WT2, WTs, weff);
    scan_block<<<NBLK, 256, 0, stream>>>(degfill, rowptr, bsum);
    scan_add2<<<(N_NODES + 256) / 256, 256, 0, stream>>>(rowptr, bsum, degfill, NBLK);

    // ===== GAT layer 1 (+ fused skip GEMM + 16B-record CSR fill) =====
    gemm_mfma_att<IN_F, false, false, true, true>
        <<<GEMM_BLKS + EB_BLK, 256, 0, stream>>>(
            x, WT1, nullptr, nullptr, nullptr, 0.f, WTs, skip_b, residual, att_src1,
            att_dst1, xsb, asrc, adst, N_NODES, ei, (const float4*)ea, rowptr, degfill,
            edrec);
    edge_w<<<EB_BLK, 256, 0, stream>>>(edrec, weff, (const float4*)asrc,
                                       (const float4*)adst, pw);
    gat_node<false><<<NODE4, 256, 0, stream>>>(rowptr, edrec, pw, (const float4*)asrc,
                                               (const float4*)adst, (const uint2*)xsb,
                                               colsum, aggb);
    // BN1 stats in position space (b1 cancels); finalize fused into gemm2 prologue
    colstats_bf<<<NBLK, 256, 0, stream>>>(aggb, colsum, colsq, N_NODES);

    // ===== GAT layer 2 (BN1 finalize+apply fused into bf16 A-load) =====
    gemm_mfma_att<HC, true, true, false, false><<<GEMM_BLKS, 256, 0, stream>>>(
        aggb, WT2, colsum, g1, be1, invM, nullptr, nullptr, nullptr, att_src2, att_dst2,
        xsb, asrc, adst, N_NODES, nullptr, nullptr, nullptr, nullptr, nullptr);
    edge_w<<<EB_BLK, 256, 0, stream>>>(edrec, weff + 16, (const float4*)asrc,
                                       (const float4*)adst, pw);
    gat_node<true><<<NODE4, 256, 0, stream>>>(rowptr, edrec, pw, (const float4*)asrc,
                                              (const float4*)adst, (const uint2*)xsb,
                                              colsum, h2);
    // BN2 stats on h2 (true-channel space, b2 cancels); finalize fused into head
    colstats<CH><<<NBLK, 256, 0, stream>>>(h2, colsum, colsq, N_NODES);

    // fused BN2-finalize + BN2+ELU+residual + MLP head
    head_mlp<<<NODE4, 256, 0, stream>>>(h2, colsum, g2, be2, invM, residual, fc1_W, fc1_b,
                                        fc2_W, fc2_b, out);
}